// Round 15
// baseline (522.590 us; speedup 1.0000x reference)
//
#include <hip/hip_runtime.h>
#include <hip/hip_bf16.h>
#include <math.h>

typedef __attribute__((ext_vector_type(8))) short short8;
typedef __attribute__((ext_vector_type(4))) float f32x4;

#define T_SEQ 2048
#define NVOC 42
#define REP_P1 25   // diagnostic: surface pre1 above the 39us harness fills
#define REP_P2 40   // diagnostic: surface pre2
#define REP_M  16   // diagnostic: surface k_main

// ws float offsets
#define OFF_UE  0        // 42*64 -> 2688
#define OFF_RE  2688     // 42*64 -> 5376
#define OFF_VE  5376     // 43*128 -> 10880
#define OFF_TAU 10880    // 42*43 = 1806 -> 12686
#define OFF_WB  12688    // u16[24 frag][64 lane][8] = 12288 u16 = 6144 f -> 18832
#define OFF_HB  18832    // u16[12 frag][64 lane][8] = 6144 u16 = 3072 f -> 21904

static __device__ __forceinline__ short f2b(float x){
  __hip_bfloat16 h = __float2bfloat16(x);
  return *reinterpret_cast<short*>(&h);
}

// pre1 (R14 body, REP_P1 idempotent reps): 128 blocks x 128 threads.
__global__ __launch_bounds__(128) void k_pre1(const float* __restrict__ emb,
    const float* __restrict__ w1, const float* __restrict__ b1,
    const float* __restrict__ wv_w, const float* __restrict__ wv_b,
    const float* __restrict__ mg_w, const float* __restrict__ mg_b,
    const float* __restrict__ head_w, float* __restrict__ ws){
  int blk = blockIdx.x, tid = threadIdx.x;
  ushort* wbu = (ushort*)(ws + OFF_WB);
  for (int rep = 0; rep < REP_P1; ++rep){
    if (blk < 42){
      if (tid < 64){
        float su = b1[tid], sr = 0.f;
        for (int i = 0; i < 128; ++i){
          float e = emb[blk*128 + i];
          su = fmaf(e, w1[i*64 + tid], su);
          sr = fmaf(e, w1[(128+i)*64 + tid], sr);
        }
        ws[OFF_UE + blk*64 + tid] = su;
        ws[OFF_RE + blk*64 + tid] = sr;
      }
    } else if (blk < 85){
      int c = blk - 42;                 // 0..42 (42 == zero-padded neighbor)
      float s = wv_b[tid];
      if (c < 42){
        for (int i = 0; i < 128; ++i) s = fmaf(emb[c*128 + i], wv_w[i*128 + tid], s);
      }
      ws[OFF_VE + c*128 + tid] = s;
    } else if (blk < 127){
      int a = blk - 85;
      float s = mg_b[tid];
      for (int i = 0; i < 128; ++i) s = fmaf(emb[a*128 + i], mg_w[i*128 + tid], s);
      int d = tid, k = 43 + a;
      wbu[(((d>>4)*3 + (k>>5))*64 + (((k>>3)&3)*16 + (d&15)))*8 + (k&7)] = (ushort)f2b(s);
    } else {
      ushort* hbu = (ushort*)(ws + OFF_HB);
      for (int i2 = tid; i2 < 6144; i2 += 128){
        int f = i2 >> 9, ln = (i2 >> 3) & 63, j = i2 & 7;
        int n2 = f >> 2, cc = f & 3;
        int k = cc*32 + (ln>>4)*8 + j;
        int col = n2*16 + (ln & 15);
        float v = (col < NVOC) ? head_w[k*NVOC + col] : 0.f;
        hbu[i2] = (ushort)f2b(v);
      }
      for (int i = tid; i < 1408; i += 128){
        int n = i/176, rem = i%176, k = 85 + rem/16, col = rem%16;
        wbu[((n*3 + 2)*64 + (((k>>3)&3)*16 + col))*8 + (k&7)] = 0;
      }
    }
    __asm__ volatile("" ::: "memory");
  }
}

// pre2 (R14 body, REP_P2 idempotent reps): 85 blocks x 128 threads.
__global__ __launch_bounds__(128) void k_pre2(const float* __restrict__ w2,
    const float* __restrict__ b2, const float* __restrict__ mg_w,
    float* __restrict__ ws){
  int blk = blockIdx.x, tid = threadIdx.x;
  ushort* wbu = (ushort*)(ws + OFF_WB);
  for (int rep = 0; rep < REP_P2; ++rep){
    if (blk < 42){
      if (tid < 43){
        float s = b2[0];
        for (int k = 0; k < 64; ++k){
          float h = ws[OFF_UE + blk*64 + k] + (tid < 42 ? ws[OFF_RE + tid*64 + k] : 0.f);
          float sg = 1.f/(1.f + __expf(-h));
          s = fmaf(h*sg, w2[k], s);
        }
        ws[OFF_TAU + blk*43 + tid] = 1.f/(1.f + __expf(-s));
      }
    } else {
      int c = blk - 42;                 // 0..42
      float s = 0.f;
      for (int i = 0; i < 128; ++i) s = fmaf(ws[OFF_VE + c*128 + i], mg_w[(128+i)*128 + tid], s);
      int d = tid, k = c;
      wbu[(((d>>4)*3 + (k>>5))*64 + (((k>>3)&3)*16 + (d&15)))*8 + (k&7)] = (ushort)f2b(s);
    }
    __asm__ volatile("" ::: "memory");
  }
}

// k_main (R14 body, REP_M idempotent reps incl. full prologue per pass).
__global__ __launch_bounds__(256) void k_main(const int* __restrict__ ids,
    const float* __restrict__ ln_g, const float* __restrict__ ln_b,
    const float* __restrict__ head_b, const float* __restrict__ ws,
    float* __restrict__ out){
  __shared__ __align__(16) float s_T[4][1600];
  int tid = threadIdx.x, wv = tid >> 6, lane = tid & 63;
  int r = lane & 15, q = lane >> 4;
  int base = blockIdx.x*64 + wv*16;
  const ushort* wbu = (const ushort*)(ws + OFF_WB);
  float* T = s_T[wv];

  for (int rep = 0; rep < REP_M; ++rep){
    int l32 = lane & 31;
    int idv = NVOC;
    if (!(((base & (T_SEQ-1)) == 0) && (l32 < 16))) idv = ids[base - 16 + l32];

    short8 HBf[3][4];
    {
      const ushort* hbsrc = (const ushort*)(ws + OFF_HB);
      #pragma unroll
      for (int n2 = 0; n2 < 3; ++n2)
        #pragma unroll
        for (int c = 0; c < 4; ++c)
          HBf[n2][c] = *(const short8*)&hbsrc[((n2*4 + c)*64 + lane)*8];
    }
    float gd[8], bd[8];
    #pragma unroll
    for (int n = 0; n < 8; ++n){ gd[n] = ln_g[n*16 + r]; bd[n] = ln_b[n*16 + r]; }
    float hb3[3];
    #pragma unroll
    for (int n2 = 0; n2 < 3; ++n2){ int col = n2*16 + r; hb3[n2] = (col < NVOC) ? head_b[col] : 0.f; }

    {
      float4 z; z.x=z.y=z.z=z.w=0.f;
      float4* t4 = (float4*)T;
      #pragma unroll
      for (int i = 0; i < 7; ++i){ int idx = lane + i*64; if (idx < 400) t4[idx] = z; }
    }
    int a = __shfl(idv, 16 + r);
    const float* tau_g = ws + OFF_TAU;
    #pragma unroll
    for (int m = 0; m < 4; ++m){
      int w = q*4 + m;
      int c = __shfl(idv, r + 15 - w);
      float tv = tau_g[a*43 + c];
      atomicAdd(&T[r*100 + c], tv);
    }
    if (q == 0) T[r*100 + 43 + a] = 1.0f;
    __asm__ volatile("s_waitcnt lgkmcnt(0)" ::: "memory");

    short8 A1[3];
    #pragma unroll
    for (int ct = 0; ct < 3; ++ct){
      const float4* p = (const float4*)&T[r*100 + ct*32 + q*8];
      float4 u0 = p[0], u1 = p[1];
      short8 v;
      v[0]=f2b(u0.x); v[1]=f2b(u0.y); v[2]=f2b(u0.z); v[3]=f2b(u0.w);
      v[4]=f2b(u1.x); v[5]=f2b(u1.y); v[6]=f2b(u1.z); v[7]=f2b(u1.w);
      A1[ct] = v;
    }

    f32x4 accm[8];
    #pragma unroll
    for (int n = 0; n < 8; ++n){ accm[n][0]=0.f; accm[n][1]=0.f; accm[n][2]=0.f; accm[n][3]=0.f; }
    #pragma unroll
    for (int ct = 0; ct < 3; ++ct){
      #pragma unroll
      for (int n = 0; n < 8; ++n){
        short8 b = *(const short8*)&wbu[((n*3 + ct)*64 + lane)*8];
        accm[n] = __builtin_amdgcn_mfma_f32_16x16x32_bf16(A1[ct], b, accm[n], 0, 0, 0);
      }
    }

    ushort* sY = (ushort*)T;
    #pragma unroll
    for (int reg = 0; reg < 4; ++reg){
      float s1 = 0.f, s2 = 0.f;
      #pragma unroll
      for (int n = 0; n < 8; ++n){ float y = accm[n][reg]; s1 += y; s2 = fmaf(y, y, s2); }
      #pragma unroll
      for (int mk = 1; mk < 16; mk <<= 1){ s1 += __shfl_xor(s1, mk); s2 += __shfl_xor(s2, mk); }
      float mu  = s1 * (1.f/128.f);
      float var = s2 * (1.f/128.f) - mu*mu;
      float rinv = rsqrtf(var + 1e-5f);
      int tok = base + q*4 + reg;
      int m12 = ((tok & (T_SEQ-1)) + 8) % 12;
      float sc = fmaf(0.15f, __sinf((float)m12 * 0.52359877559829887f), 1.0f);
      float A_ = rinv * sc;
      #pragma unroll
      for (int n = 0; n < 8; ++n){
        float yl = (accm[n][reg] - mu) * A_;
        float o  = fmaf(yl, gd[n], bd[n]*sc);
        sY[(q*4 + reg)*136 + n*16 + r] = (ushort)f2b(o);
      }
    }

    f32x4 acch[3];
    #pragma unroll
    for (int n2 = 0; n2 < 3; ++n2){ acch[n2][0]=0.f; acch[n2][1]=0.f; acch[n2][2]=0.f; acch[n2][3]=0.f; }
    short8 A2[4];
    #pragma unroll
    for (int c = 0; c < 4; ++c)
      A2[c] = *(const short8*)&sY[r*136 + c*32 + q*8];
    #pragma unroll
    for (int c = 0; c < 4; ++c){
      #pragma unroll
      for (int n2 = 0; n2 < 3; ++n2)
        acch[n2] = __builtin_amdgcn_mfma_f32_16x16x32_bf16(A2[c], HBf[n2][c], acch[n2], 0, 0, 0);
    }
    #pragma unroll
    for (int n2 = 0; n2 < 3; ++n2){
      int col = n2*16 + r;
      if (col < NVOC){
        #pragma unroll
        for (int reg = 0; reg < 4; ++reg){
          int tok = base + q*4 + reg;
          out[tok*NVOC + col] = acch[n2][reg] + hb3[n2];
        }
      }
    }
    __asm__ volatile("" ::: "memory");
  }
}

extern "C" void kernel_launch(void* const* d_in, const int* in_sizes, int n_in,
                              void* d_out, int out_size, void* d_ws, size_t ws_size,
                              hipStream_t stream){
  const int*   ids    = (const int*)  d_in[0];
  const float* emb    = (const float*)d_in[1];
  const float* w1     = (const float*)d_in[2];
  const float* b1     = (const float*)d_in[3];
  const float* w2     = (const float*)d_in[4];
  const float* b2     = (const float*)d_in[5];
  const float* wv_w   = (const float*)d_in[6];
  const float* wv_b   = (const float*)d_in[7];
  const float* mg_w   = (const float*)d_in[8];
  const float* mg_b   = (const float*)d_in[9];
  const float* ln_g   = (const float*)d_in[10];
  const float* ln_b   = (const float*)d_in[11];
  const float* head_w = (const float*)d_in[12];
  const float* head_b = (const float*)d_in[13];
  float* ws  = (float*)d_ws;
  float* out = (float*)d_out;
  k_pre1<<<dim3(128), dim3(128), 0, stream>>>(emb, w1, b1, wv_w, wv_b, mg_w, mg_b,
                                              head_w, ws);
  k_pre2<<<dim3(85),  dim3(128), 0, stream>>>(w2, b2, mg_w, ws);
  k_main<<<dim3(512), dim3(256), 0, stream>>>(ids, ln_g, ln_b, head_b, ws, out);
}

// Round 16
// 22.945 us; speedup vs baseline: 22.7753x; 22.7753x over previous
//
#include <hip/hip_runtime.h>
#include <hip/hip_bf16.h>
#include <math.h>

typedef __attribute__((ext_vector_type(8))) short short8;
typedef __attribute__((ext_vector_type(4))) float f32x4;

#define T_SEQ 2048
#define NVOC 42

// ws float offsets
#define OFF_UE  0        // 42*64 -> 2688
#define OFF_RE  2688     // 42*64 -> 5376
#define OFF_VE  5376     // 43*128 -> 10880
#define OFF_TAU 10880    // 42*43 = 1806 -> 12686
#define OFF_WB  12688    // u16[24 frag][64 lane][8] = 12288 u16 = 6144 f -> 18832
#define OFF_HB  18832    // u16[12 frag][64 lane][8] = 6144 u16 = 3072 f -> 21904

static __device__ __forceinline__ short f2b(float x){
  __hip_bfloat16 h = __float2bfloat16(x);
  return *reinterpret_cast<short*>(&h);
}

// pre1: split-K, short chains (R15 lesson: serial 128-dots = 8.7us latency-bound).
// 128 blocks x 256 threads. Row staged in LDS; weights reg-batched 16x; 2-way K-split.
//  0..41  : ue[a] (+b1) and re[a] rows      (o<64: ue col o; o>=64: re col o-64)
//  42..84 : ve[c] rows (c=42 -> wv_b pad)
//  85..126: ya[a] -> wb bf16 row k=43+a
//  127    : HBf pack + wb zero rows k=85..95
__global__ __launch_bounds__(256) void k_pre1(const float* __restrict__ emb,
    const float* __restrict__ w1, const float* __restrict__ b1,
    const float* __restrict__ wv_w, const float* __restrict__ wv_b,
    const float* __restrict__ mg_w, const float* __restrict__ mg_b,
    const float* __restrict__ head_w, float* __restrict__ ws){
  __shared__ __align__(16) float s_e[128];
  __shared__ __align__(16) float s_p[256];
  int blk = blockIdx.x, tid = threadIdx.x;
  ushort* wbu = (ushort*)(ws + OFF_WB);
  if (blk < 127){
    int mode = (blk < 42) ? 0 : ((blk < 85) ? 1 : 2);
    int row  = (mode == 0) ? blk : ((mode == 1) ? blk - 42 : blk - 85);
    bool pad = (mode == 1 && row == 42);
    if (tid < 128) s_e[tid] = pad ? 0.f : emb[row*128 + tid];
    __syncthreads();
    int o = tid & 127, h = tid >> 7;
    float acc = 0.f;
    if (mode == 0){
      int col = o & 63;
      const float* wp = w1 + ((o < 64) ? 0 : 128*64) + (h*64)*64 + col;
      const float* ep = s_e + h*64;
      #pragma unroll
      for (int chunk = 0; chunk < 4; ++chunk){
        float wreg[16];
        #pragma unroll
        for (int j = 0; j < 16; ++j) wreg[j] = wp[(chunk*16 + j)*64];
        #pragma unroll
        for (int j = 0; j < 16; ++j) acc = fmaf(ep[chunk*16 + j], wreg[j], acc);
      }
    } else {
      const float* wm = (mode == 1) ? wv_w : mg_w;
      const float* wp = wm + (h*64)*128 + o;
      const float* ep = s_e + h*64;
      #pragma unroll
      for (int chunk = 0; chunk < 4; ++chunk){
        float wreg[16];
        #pragma unroll
        for (int j = 0; j < 16; ++j) wreg[j] = wp[(chunk*16 + j)*128];
        #pragma unroll
        for (int j = 0; j < 16; ++j) acc = fmaf(ep[chunk*16 + j], wreg[j], acc);
      }
    }
    s_p[h*128 + o] = acc;
    __syncthreads();
    if (h == 0){
      float v = s_p[o] + s_p[128 + o];
      if (mode == 0){
        if (o < 64) ws[OFF_UE + row*64 + o] = v + b1[o];
        else        ws[OFF_RE + row*64 + (o - 64)] = v;
      } else if (mode == 1){
        ws[OFF_VE + row*128 + o] = v + wv_b[o];
      } else {
        float ya = v + mg_b[o];
        int d = o, k = 43 + row;
        wbu[(((d>>4)*3 + (k>>5))*64 + (((k>>3)&3)*16 + (d&15)))*8 + (k&7)] = (ushort)f2b(ya);
      }
    }
  } else {
    ushort* hbu = (ushort*)(ws + OFF_HB);
    for (int i2 = tid; i2 < 6144; i2 += 256){
      int f = i2 >> 9, ln = (i2 >> 3) & 63, j = i2 & 7;
      int n2 = f >> 2, cc = f & 3;
      int k = cc*32 + (ln>>4)*8 + j;
      int col = n2*16 + (ln & 15);
      float v = (col < NVOC) ? head_w[k*NVOC + col] : 0.f;
      hbu[i2] = (ushort)f2b(v);
    }
    for (int i = tid; i < 1408; i += 256){
      int n = i/176, rem = i%176, k = 85 + rem/16, col = rem%16;
      wbu[((n*3 + 2)*64 + (((k>>3)&3)*16 + col))*8 + (k&7)] = 0;
    }
  }
}

// pre2: split-K. 85 blocks x 256 threads.
//  0..41 : tau row a — 4-way K-split (16 silu-FMAs/thread) + LDS combine
//  42..84: vm[c] = ve[c] @ mg_w[128:] — 2-way K-split -> wb bf16 row k=c
__global__ __launch_bounds__(256) void k_pre2(const float* __restrict__ w2,
    const float* __restrict__ b2, const float* __restrict__ mg_w,
    float* __restrict__ ws){
  __shared__ __align__(16) float s_v[128];
  __shared__ __align__(16) float s_p[256];
  int blk = blockIdx.x, tid = threadIdx.x;
  ushort* wbu = (ushort*)(ws + OFF_WB);
  if (blk < 42){
    int a = blk;
    if (tid < 64) s_v[tid] = ws[OFF_UE + a*64 + tid];
    __syncthreads();
    int o = tid & 63, h = tid >> 6;             // o = c, h = K-quarter
    float part = 0.f;
    if (o < 43){
      float rreg[16], wreg[16];
      #pragma unroll
      for (int j = 0; j < 16; ++j){
        int k = h*16 + j;
        rreg[j] = (o < 42) ? ws[OFF_RE + o*64 + k] : 0.f;
        wreg[j] = w2[k];
      }
      #pragma unroll
      for (int j = 0; j < 16; ++j){
        float hh = s_v[h*16 + j] + rreg[j];
        float sg = 1.f/(1.f + __expf(-hh));
        part = fmaf(hh*sg, wreg[j], part);
      }
    }
    s_p[h*64 + o] = part;
    __syncthreads();
    if (h == 0 && o < 43){
      float s = s_p[o] + s_p[64+o] + s_p[128+o] + s_p[192+o] + b2[0];
      ws[OFF_TAU + a*43 + o] = 1.f/(1.f + __expf(-s));
    }
  } else {
    int c = blk - 42;
    if (tid < 128) s_v[tid] = ws[OFF_VE + c*128 + tid];
    __syncthreads();
    int o = tid & 127, h = tid >> 7;
    const float* wp = mg_w + (128 + h*64)*128 + o;
    const float* vp = s_v + h*64;
    float acc = 0.f;
    #pragma unroll
    for (int chunk = 0; chunk < 4; ++chunk){
      float wreg[16];
      #pragma unroll
      for (int j = 0; j < 16; ++j) wreg[j] = wp[(chunk*16 + j)*128];
      #pragma unroll
      for (int j = 0; j < 16; ++j) acc = fmaf(vp[chunk*16 + j], wreg[j], acc);
    }
    s_p[h*128 + o] = acc;
    __syncthreads();
    if (h == 0){
      float vm = s_p[o] + s_p[128 + o];
      int d = o, k = c;
      wbu[(((d>>4)*3 + (k>>5))*64 + (((k>>3)&3)*16 + (d&15)))*8 + (k&7)] = (ushort)f2b(vm);
    }
  }
}

// Main: per wave 16 tokens, wave-independent, ZERO barriers (validated R14 body).
__global__ __launch_bounds__(256) void k_main(const int* __restrict__ ids,
    const float* __restrict__ ln_g, const float* __restrict__ ln_b,
    const float* __restrict__ head_b, const float* __restrict__ ws,
    float* __restrict__ out){
  __shared__ __align__(16) float s_T[4][1600];
  int tid = threadIdx.x, wv = tid >> 6, lane = tid & 63;
  int r = lane & 15, q = lane >> 4;
  int base = blockIdx.x*64 + wv*16;
  const ushort* wbu = (const ushort*)(ws + OFF_WB);

  int l32 = lane & 31;
  int idv = NVOC;
  if (!(((base & (T_SEQ-1)) == 0) && (l32 < 16))) idv = ids[base - 16 + l32];

  short8 HBf[3][4];
  {
    const ushort* hbsrc = (const ushort*)(ws + OFF_HB);
    #pragma unroll
    for (int n2 = 0; n2 < 3; ++n2)
      #pragma unroll
      for (int c = 0; c < 4; ++c)
        HBf[n2][c] = *(const short8*)&hbsrc[((n2*4 + c)*64 + lane)*8];
  }
  float gd[8], bd[8];
  #pragma unroll
  for (int n = 0; n < 8; ++n){ gd[n] = ln_g[n*16 + r]; bd[n] = ln_b[n*16 + r]; }
  float hb3[3];
  #pragma unroll
  for (int n2 = 0; n2 < 3; ++n2){ int col = n2*16 + r; hb3[n2] = (col < NVOC) ? head_b[col] : 0.f; }

  float* T = s_T[wv];
  {
    float4 z; z.x=z.y=z.z=z.w=0.f;
    float4* t4 = (float4*)T;
    #pragma unroll
    for (int i = 0; i < 7; ++i){ int idx = lane + i*64; if (idx < 400) t4[idx] = z; }
  }
  int a = __shfl(idv, 16 + r);
  const float* tau_g = ws + OFF_TAU;
  #pragma unroll
  for (int m = 0; m < 4; ++m){
    int w = q*4 + m;
    int c = __shfl(idv, r + 15 - w);
    float tv = tau_g[a*43 + c];
    atomicAdd(&T[r*100 + c], tv);
  }
  if (q == 0) T[r*100 + 43 + a] = 1.0f;
  __asm__ volatile("s_waitcnt lgkmcnt(0)" ::: "memory");

  short8 A1[3];
  #pragma unroll
  for (int ct = 0; ct < 3; ++ct){
    const float4* p = (const float4*)&T[r*100 + ct*32 + q*8];
    float4 u0 = p[0], u1 = p[1];
    short8 v;
    v[0]=f2b(u0.x); v[1]=f2b(u0.y); v[2]=f2b(u0.z); v[3]=f2b(u0.w);
    v[4]=f2b(u1.x); v[5]=f2b(u1.y); v[6]=f2b(u1.z); v[7]=f2b(u1.w);
    A1[ct] = v;
  }

  f32x4 accm[8];
  #pragma unroll
  for (int n = 0; n < 8; ++n){ accm[n][0]=0.f; accm[n][1]=0.f; accm[n][2]=0.f; accm[n][3]=0.f; }
  #pragma unroll
  for (int ct = 0; ct < 3; ++ct){
    #pragma unroll
    for (int n = 0; n < 8; ++n){
      short8 b = *(const short8*)&wbu[((n*3 + ct)*64 + lane)*8];
      accm[n] = __builtin_amdgcn_mfma_f32_16x16x32_bf16(A1[ct], b, accm[n], 0, 0, 0);
    }
  }

  ushort* sY = (ushort*)T;
  #pragma unroll
  for (int reg = 0; reg < 4; ++reg){
    float s1 = 0.f, s2 = 0.f;
    #pragma unroll
    for (int n = 0; n < 8; ++n){ float y = accm[n][reg]; s1 += y; s2 = fmaf(y, y, s2); }
    #pragma unroll
    for (int mk = 1; mk < 16; mk <<= 1){ s1 += __shfl_xor(s1, mk); s2 += __shfl_xor(s2, mk); }
    float mu  = s1 * (1.f/128.f);
    float var = s2 * (1.f/128.f) - mu*mu;
    float rinv = rsqrtf(var + 1e-5f);
    int tok = base + q*4 + reg;
    int m12 = ((tok & (T_SEQ-1)) + 8) % 12;
    float sc = fmaf(0.15f, __sinf((float)m12 * 0.52359877559829887f), 1.0f);
    float A_ = rinv * sc;
    #pragma unroll
    for (int n = 0; n < 8; ++n){
      float yl = (accm[n][reg] - mu) * A_;
      float o  = fmaf(yl, gd[n], bd[n]*sc);
      sY[(q*4 + reg)*136 + n*16 + r] = (ushort)f2b(o);
    }
  }

  f32x4 acch[3];
  #pragma unroll
  for (int n2 = 0; n2 < 3; ++n2){ acch[n2][0]=0.f; acch[n2][1]=0.f; acch[n2][2]=0.f; acch[n2][3]=0.f; }
  short8 A2[4];
  #pragma unroll
  for (int c = 0; c < 4; ++c)
    A2[c] = *(const short8*)&sY[r*136 + c*32 + q*8];
  #pragma unroll
  for (int c = 0; c < 4; ++c){
    #pragma unroll
    for (int n2 = 0; n2 < 3; ++n2)
      acch[n2] = __builtin_amdgcn_mfma_f32_16x16x32_bf16(A2[c], HBf[n2][c], acch[n2], 0, 0, 0);
  }
  #pragma unroll
  for (int n2 = 0; n2 < 3; ++n2){
    int col = n2*16 + r;
    if (col < NVOC){
      #pragma unroll
      for (int reg = 0; reg < 4; ++reg){
        int tok = base + q*4 + reg;
        out[tok*NVOC + col] = acch[n2][reg] + hb3[n2];
      }
    }
  }
}

extern "C" void kernel_launch(void* const* d_in, const int* in_sizes, int n_in,
                              void* d_out, int out_size, void* d_ws, size_t ws_size,
                              hipStream_t stream){
  const int*   ids    = (const int*)  d_in[0];
  const float* emb    = (const float*)d_in[1];
  const float* w1     = (const float*)d_in[2];
  const float* b1     = (const float*)d_in[3];
  const float* w2     = (const float*)d_in[4];
  const float* b2     = (const float*)d_in[5];
  const float* wv_w   = (const float*)d_in[6];
  const float* wv_b   = (const float*)d_in[7];
  const float* mg_w   = (const float*)d_in[8];
  const float* mg_b   = (const float*)d_in[9];
  const float* ln_g   = (const float*)d_in[10];
  const float* ln_b   = (const float*)d_in[11];
  const float* head_w = (const float*)d_in[12];
  const float* head_b = (const float*)d_in[13];
  float* ws  = (float*)d_ws;
  float* out = (float*)d_out;
  k_pre1<<<dim3(128), dim3(256), 0, stream>>>(emb, w1, b1, wv_w, wv_b, mg_w, mg_b,
                                              head_w, ws);
  k_pre2<<<dim3(85),  dim3(256), 0, stream>>>(w2, b2, mg_w, ws);
  k_main<<<dim3(512), dim3(256), 0, stream>>>(ids, ln_g, ln_b, head_b, ws, out);
}